// Round 8
// baseline (34.798 us; speedup 1.0000x reference)
//
#include <hip/hip_runtime.h>
#include <math.h>

#define B 4
#define S 4096
#define N 4096
#define BLK1 256
#define SPT 8             // grid points per thread
#define NCHUNK 128
#define CSIZE 32          // N / NCHUNK
#define SUBC 16           // cloud points per SGPR stage (16 float4 = 64 SGPRs)
#define BLK2 256
#define CSPLIT 8
#define CPG (NCHUNK / CSPLIT)   // 16
#define INF 3.4e38f

// Kernel 1: each thread owns SPT grid points. Cloud chunk is read via
// block-uniform float4 loads into uniform locals (-> SGPRs via scalar loads),
// 16 points at a time, one cloud at a time; inner loop is pure VALU:
// t = hy - x.y (Gram form), acc = min. No LDS, no syncthreads.
// Writes u = max(hx + min t, 0) as fp32 partials [2][NCHUNK][B][S].
__global__ __launch_bounds__(BLK1) void sdf_partial_min(
    const float* __restrict__ grid,   // [B,S,3]
    const float* __restrict__ gts,    // [B,N,3]
    const float* __restrict__ preds,  // [B,N,3]
    float* __restrict__ partial)      // [2][NCHUNK][B][S]
{
    const int tid   = threadIdx.x;
    const int stile = blockIdx.x;            // 2 tiles of 2048 s
    const int chunk = blockIdx.y;            // 128 chunks of 32 pts
    const int b     = blockIdx.z;

    const int s0 = stile * (BLK1 * SPT) + tid;   // gp i at s0 + i*BLK1

    float x0[SPT], x1[SPT], x2[SPT], hx[SPT];
    #pragma unroll
    for (int i = 0; i < SPT; ++i) {
        const float* xp = grid + ((size_t)b * S + s0 + i * BLK1) * 3;
        x0[i] = -xp[0]; x1[i] = -xp[1]; x2[i] = -xp[2];
        hx[i] = 0.5f * (x0[i] * x0[i] + x1[i] * x1[i] + x2[i] * x2[i]);
    }

    const int n0 = chunk * CSIZE;
    // Block-uniform base pointers (float, 3 per point).
    const float* pbase = preds + ((size_t)b * N + n0) * 3;
    const float* gbase = gts   + ((size_t)b * N + n0) * 3;

    float accp[SPT], accg[SPT];
    #pragma unroll
    for (int i = 0; i < SPT; ++i) { accp[i] = INF; accg[i] = INF; }

    // Two 16-point sub-chunks; per sub-chunk, process preds then gts
    // sequentially so only one cloud's 16 uniform float4 (64 scalars) is
    // live at a time.
    #pragma unroll
    for (int sc = 0; sc < CSIZE / SUBC; ++sc) {
        // ---- preds ----
        {
            const float* cb = pbase + sc * SUBC * 3;  // 16 pts * 3 floats
            float cx[SUBC], cy[SUBC], cz[SUBC], ch[SUBC];
            #pragma unroll
            for (int j = 0; j < SUBC; ++j) {
                cx[j] = cb[3 * j + 0];
                cy[j] = cb[3 * j + 1];
                cz[j] = cb[3 * j + 2];
                ch[j] = 0.5f * (cx[j] * cx[j] + cy[j] * cy[j] + cz[j] * cz[j]);
            }
            #pragma unroll
            for (int j = 0; j < SUBC; j += 4) {
                #pragma unroll
                for (int i = 0; i < SPT; ++i) {
                    float a0 = fmaf(x0[i], cx[j+0], fmaf(x1[i], cy[j+0], fmaf(x2[i], cz[j+0], ch[j+0])));
                    float a1 = fmaf(x0[i], cx[j+1], fmaf(x1[i], cy[j+1], fmaf(x2[i], cz[j+1], ch[j+1])));
                    float a2 = fmaf(x0[i], cx[j+2], fmaf(x1[i], cy[j+2], fmaf(x2[i], cz[j+2], ch[j+2])));
                    float a3 = fmaf(x0[i], cx[j+3], fmaf(x1[i], cy[j+3], fmaf(x2[i], cz[j+3], ch[j+3])));
                    accp[i] = fminf(fminf(accp[i], fminf(a0, a1)), fminf(a2, a3));
                }
            }
        }
        // ---- gts ----
        {
            const float* cb = gbase + sc * SUBC * 3;
            float cx[SUBC], cy[SUBC], cz[SUBC], ch[SUBC];
            #pragma unroll
            for (int j = 0; j < SUBC; ++j) {
                cx[j] = cb[3 * j + 0];
                cy[j] = cb[3 * j + 1];
                cz[j] = cb[3 * j + 2];
                ch[j] = 0.5f * (cx[j] * cx[j] + cy[j] * cy[j] + cz[j] * cz[j]);
            }
            #pragma unroll
            for (int j = 0; j < SUBC; j += 4) {
                #pragma unroll
                for (int i = 0; i < SPT; ++i) {
                    float a0 = fmaf(x0[i], cx[j+0], fmaf(x1[i], cy[j+0], fmaf(x2[i], cz[j+0], ch[j+0])));
                    float a1 = fmaf(x0[i], cx[j+1], fmaf(x1[i], cy[j+1], fmaf(x2[i], cz[j+1], ch[j+1])));
                    float a2 = fmaf(x0[i], cx[j+2], fmaf(x1[i], cy[j+2], fmaf(x2[i], cz[j+2], ch[j+2])));
                    float a3 = fmaf(x0[i], cx[j+3], fmaf(x1[i], cy[j+3], fmaf(x2[i], cz[j+3], ch[j+3])));
                    accg[i] = fminf(fminf(accg[i], fminf(a0, a1)), fminf(a2, a3));
                }
            }
        }
    }

    #pragma unroll
    for (int i = 0; i < SPT; ++i) {
        const size_t sidx = (size_t)b * S + s0 + i * BLK1;
        const size_t cidx = (size_t)chunk * (B * S) + sidx;
        partial[cidx] = fmaxf(hx[i] + accp[i], 0.f);
        partial[(size_t)NCHUNK * (B * S) + cidx] = fmaxf(hx[i] + accg[i], 0.f);
    }
}

// Kernel 2a: per (tile,b,cs): min over CPG chunks (coalesced fp32 reads),
// write part2[cs][cloud][b][s].
__global__ __launch_bounds__(BLK2) void sdf_reduce_a(
    const float* __restrict__ partial, float* __restrict__ part2)
{
    const int tile = blockIdx.x;
    const int b    = blockIdx.y;
    const int cs   = blockIdx.z;
    const int tid  = threadIdx.x;
    const int s    = tile * BLK2 + tid;

    const size_t bs = (size_t)B * S;
    const size_t base = (size_t)b * S + s;

    float mp = INF, mg = INF;
    #pragma unroll
    for (int c = 0; c < CPG; ++c) {
        const size_t cidx = (size_t)(cs * CPG + c) * bs + base;
        mp = fminf(mp, partial[cidx]);
        mg = fminf(mg, partial[(size_t)NCHUNK * bs + cidx]);
    }
    part2[(size_t)(cs * 2 + 0) * bs + base] = mp;
    part2[(size_t)(cs * 2 + 1) * bs + base] = mg;
}

// Kernel 2b: per (tile,b): min over CSPLIT groups, d = sqrt(2u), |diff|,
// block-sum -> pb[b*ntile + tile].
__global__ __launch_bounds__(BLK2) void sdf_reduce_b(
    const float* __restrict__ part2, float* __restrict__ pb)
{
    const int tile = blockIdx.x;
    const int b    = blockIdx.y;
    const int tid  = threadIdx.x;
    const int s    = tile * BLK2 + tid;

    const size_t bs = (size_t)B * S;
    const size_t base = (size_t)b * S + s;

    float mp = INF, mg = INF;
    #pragma unroll
    for (int cs = 0; cs < CSPLIT; ++cs) {
        mp = fminf(mp, part2[(size_t)(cs * 2 + 0) * bs + base]);
        mg = fminf(mg, part2[(size_t)(cs * 2 + 1) * bs + base]);
    }

    float v = fabsf(sqrtf(fmaxf(2.f * mp, 0.f)) - sqrtf(fmaxf(2.f * mg, 0.f)));

    #pragma unroll
    for (int off = 32; off > 0; off >>= 1)
        v += __shfl_down(v, off, 64);

    __shared__ float wsum[BLK2 / 64];
    if ((tid & 63) == 0) wsum[tid >> 6] = v;
    __syncthreads();
    if (tid == 0) {
        float t = 0.f;
        #pragma unroll
        for (int w = 0; w < BLK2 / 64; ++w) t += wsum[w];
        pb[b * gridDim.x + tile] = t;
    }
}

// Kernel 3: final tiny reduction (ntile=16 partials per batch).
__global__ __launch_bounds__(64) void sdf_final(
    const float* __restrict__ pb, float* __restrict__ out)
{
    const int tid = threadIdx.x;
    const int ntile = S / BLK2;   // 16
    float v = (tid < B * ntile) ? pb[tid] : 0.f;
    #pragma unroll
    for (int off = 8; off > 0; off >>= 1)
        v += __shfl_down(v, off, 16);
    if (tid < B * ntile && (tid & 15) == 0)
        out[tid / 16] = v / (float)S;
}

extern "C" void kernel_launch(void* const* d_in, const int* in_sizes, int n_in,
                              void* d_out, int out_size, void* d_ws, size_t ws_size,
                              hipStream_t stream) {
    const float* grid  = (const float*)d_in[0];
    const float* gts   = (const float*)d_in[1];
    const float* preds = (const float*)d_in[2];
    float* out = (float*)d_out;

    // ws layout: partial fp32 16.8 MB @0 | part2 fp32 1 MB @32MB | pb @48MB
    float* partial = (float*)d_ws;
    float* part2   = (float*)((char*)d_ws + (32u << 20));
    float* pb      = (float*)((char*)d_ws + (48u << 20));

    dim3 g1(S / (BLK1 * SPT), NCHUNK, B);    // (2, 128, 4) = 1024 blocks
    sdf_partial_min<<<g1, BLK1, 0, stream>>>(grid, gts, preds, partial);

    dim3 g2a(S / BLK2, B, CSPLIT);           // (16, 4, 8) = 512 blocks
    sdf_reduce_a<<<g2a, BLK2, 0, stream>>>(partial, part2);

    dim3 g2b(S / BLK2, B);                   // (16, 4) = 64 blocks
    sdf_reduce_b<<<g2b, BLK2, 0, stream>>>(part2, pb);

    sdf_final<<<1, 64, 0, stream>>>(pb, out);
}